// Round 1
// baseline (5012.485 us; speedup 1.0000x reference)
//
#include <hip/hip_runtime.h>

constexpr int Uc = 100000;
constexpr int Ic = 50000;
constexpr int Nc = 150000;   // U + I
constexpr int Ec = 1000000;
constexpr int Bc = 16384;

// ---------------- kernels ----------------

// Fp[d] = sum_j F[d][j] * proj_w[j]   (64x64 @ 64 -> 64)
__global__ void k_fproj(const float* __restrict__ F, const float* __restrict__ pw,
                        float* __restrict__ Fp) {
    int d = threadIdx.x;
    if (d < 64) {
        float s = 0.f;
#pragma unroll
        for (int j = 0; j < 64; ++j) s += F[d * 64 + j] * pw[j];
        Fp[d] = s;
    }
}

// ew[e] = dot(edge_features[e,:], Fp) + proj_b ; 16 lanes per edge, float4 loads
__global__ void k_ew(const float* __restrict__ ef, const float* __restrict__ Fp,
                     const float* __restrict__ pb, float* __restrict__ ew) {
    int t = blockIdx.x * blockDim.x + threadIdx.x;
    int e = t >> 4, l = t & 15;
    if (e >= Ec) return;
    float4 f = reinterpret_cast<const float4*>(ef)[e * 16 + l];
    float4 w = reinterpret_cast<const float4*>(Fp)[l];
    float s = f.x * w.x + f.y * w.y + f.z * w.z + f.w * w.w;
    s += __shfl_xor(s, 8, 16);
    s += __shfl_xor(s, 4, 16);
    s += __shfl_xor(s, 2, 16);
    s += __shfl_xor(s, 1, 16);
    if (l == 0) ew[e] = s + pb[0];
}

// degree count over the 2E dst indices
__global__ void k_deg(const int* __restrict__ dst, unsigned* __restrict__ deg) {
    int t = blockIdx.x * blockDim.x + threadIdx.x;
    if (t < 2 * Ec) atomicAdd(&deg[dst[t]], 1u);
}

__global__ void k_dinv(const unsigned* __restrict__ deg, float* __restrict__ dinv) {
    int t = blockIdx.x * blockDim.x + threadIdx.x;
    if (t < Nc) {
        unsigned d = deg[t];
        dinv[t] = d ? rsqrtf((float)d) : 0.f;
    }
}

// x0 = concat(Gu, Gi), float4-vectorized copy
__global__ void k_initx(const float* __restrict__ Gu, const float* __restrict__ Gi,
                        float4* __restrict__ x) {
    int t = blockIdx.x * blockDim.x + threadIdx.x;  // over Nc*16 float4s
    if (t >= Nc * 16) return;
    x[t] = (t < Uc * 16) ? reinterpret_cast<const float4*>(Gu)[t]
                         : reinterpret_cast<const float4*>(Gi)[t - Uc * 16];
}

// acc_u[b] (+)= alpha * x[users[b]] ; acc_i[b] (+)= alpha * x[U + items[b]]
__global__ void k_gather(const float* __restrict__ x, const int* __restrict__ users,
                         const int* __restrict__ items, float* __restrict__ accu,
                         float* __restrict__ acci, float alpha, int first) {
    int t = blockIdx.x * blockDim.x + threadIdx.x;
    int r = t >> 4, l = t & 15;
    if (r >= 2 * Bc) return;
    int b, node;
    float* acc;
    if (r < Bc) { b = r; node = users[b]; acc = accu; }
    else        { b = r - Bc; node = Uc + items[b]; acc = acci; }
    float4 v = reinterpret_cast<const float4*>(x)[node * 16 + l];
    float4* ap = reinterpret_cast<float4*>(acc) + b * 16 + l;
    if (first) {
        *ap = make_float4(alpha * v.x, alpha * v.y, alpha * v.z, alpha * v.w);
    } else {
        float4 a = *ap;
        a.x += alpha * v.x; a.y += alpha * v.y; a.z += alpha * v.z; a.w += alpha * v.w;
        *ap = a;
    }
}

// scatter: xn[dst] += dinv[src]*dinv[dst]*ew[e] * x[src]  (16 lanes/edge)
__global__ void k_prop(const int* __restrict__ src, const int* __restrict__ dst,
                       const float* __restrict__ ew, const float* __restrict__ dinv,
                       const float* __restrict__ x, float* __restrict__ xn) {
    int t = blockIdx.x * blockDim.x + threadIdx.x;
    int e = t >> 4, l = t & 15;
    if (e >= 2 * Ec) return;
    int s = src[e], d = dst[e];
    float c = dinv[s] * dinv[d] * ew[(e >= Ec) ? (e - Ec) : e];
    if (c == 0.f) return;
    float4 v = reinterpret_cast<const float4*>(x)[s * 16 + l];
    float* dp = xn + (size_t)d * 64 + l * 4;
    atomicAdd(dp + 0, c * v.x);
    atomicAdd(dp + 1, c * v.y);
    atomicAdd(dp + 2, c * v.z);
    atomicAdd(dp + 3, c * v.w);
}

// out[b] = dot(acc_u[b], acc_i[b])
__global__ void k_score(const float* __restrict__ accu, const float* __restrict__ acci,
                        float* __restrict__ out) {
    int t = blockIdx.x * blockDim.x + threadIdx.x;
    int b = t >> 4, l = t & 15;
    if (b >= Bc) return;
    float4 a = reinterpret_cast<const float4*>(accu)[b * 16 + l];
    float4 c = reinterpret_cast<const float4*>(acci)[b * 16 + l];
    float s = a.x * c.x + a.y * c.y + a.z * c.z + a.w * c.w;
    s += __shfl_xor(s, 8, 16);
    s += __shfl_xor(s, 4, 16);
    s += __shfl_xor(s, 2, 16);
    s += __shfl_xor(s, 1, 16);
    if (l == 0) out[b] = s;
}

// ---------------- launch ----------------

extern "C" void kernel_launch(void* const* d_in, const int* in_sizes, int n_in,
                              void* d_out, int out_size, void* d_ws, size_t ws_size,
                              hipStream_t stream) {
    const float* Gu = (const float*)d_in[0];
    const float* Gi = (const float*)d_in[1];
    const float* F  = (const float*)d_in[2];
    const float* pw = (const float*)d_in[3];
    const float* pb = (const float*)d_in[4];
    const float* ef = (const float*)d_in[5];
    const int*   ei = (const int*)d_in[6];   // [2, 2E] int32
    const int* users = (const int*)d_in[7];
    const int* items = (const int*)d_in[8];
    float* out = (float*)d_out;

    float* ws = (float*)d_ws;
    float* Fp   = ws;                      // 64
    float* ew   = ws + 64;                 // E
    float* dinv = ew + Ec;                 // N
    unsigned* deg = (unsigned*)(dinv + Nc);// N
    float* xa   = (float*)(deg + Nc);      // N*64
    float* xb   = xa + (size_t)Nc * 64;    // N*64
    float* accu = xb + (size_t)Nc * 64;    // B*64
    float* acci = accu + (size_t)Bc * 64;  // B*64

    const int* esrc = ei;
    const int* edst = ei + 2 * Ec;

    hipMemsetAsync(deg, 0, Nc * sizeof(unsigned), stream);
    k_fproj<<<1, 64, 0, stream>>>(F, pw, Fp);
    k_ew<<<(Ec * 16) / 256, 256, 0, stream>>>(ef, Fp, pb, ew);
    k_deg<<<(2 * Ec + 255) / 256, 256, 0, stream>>>(edst, deg);
    k_dinv<<<(Nc + 255) / 256, 256, 0, stream>>>(deg, dinv);
    k_initx<<<(Nc * 16 + 255) / 256, 256, 0, stream>>>(Gu, Gi, (float4*)xa);
    k_gather<<<(2 * Bc * 16) / 256, 256, 0, stream>>>(xa, users, items, accu, acci, 1.0f, 1);

    const float alphas[3] = {0.5f, 1.f / 3.f, 0.25f};
    float* xc = xa;
    float* xn = xb;
    for (int k = 0; k < 3; ++k) {
        hipMemsetAsync(xn, 0, (size_t)Nc * 64 * sizeof(float), stream);
        k_prop<<<(2 * Ec * 16) / 256, 256, 0, stream>>>(esrc, edst, ew, dinv, xc, xn);
        k_gather<<<(2 * Bc * 16) / 256, 256, 0, stream>>>(xn, users, items, accu, acci, alphas[k], 0);
        float* tmp = xc; xc = xn; xn = tmp;
    }
    k_score<<<(Bc * 16) / 256, 256, 0, stream>>>(accu, acci, out);
}

// Round 2
// 584.436 us; speedup vs baseline: 8.5766x; 8.5766x over previous
//
#include <hip/hip_runtime.h>

constexpr int Uc = 100000;
constexpr int Ic = 50000;
constexpr int Nc = 150000;   // U + I
constexpr int Ec = 1000000;
constexpr int Bc = 16384;
constexpr int NBS = (Nc + 1023) / 1024;  // scan blocks = 147

// ---------------- kernels ----------------

// Fp[d] = sum_j F[d][j] * proj_w[j]
__global__ void k_fproj(const float* __restrict__ F, const float* __restrict__ pw,
                        float* __restrict__ Fp) {
    int d = threadIdx.x;
    if (d < 64) {
        float s = 0.f;
#pragma unroll
        for (int j = 0; j < 64; ++j) s += F[d * 64 + j] * pw[j];
        Fp[d] = s;
    }
}

// ew[e] = dot(edge_features[e,:], Fp) + proj_b ; 16 lanes per edge
__global__ void k_ew(const float* __restrict__ ef, const float* __restrict__ Fp,
                     const float* __restrict__ pb, float* __restrict__ ew) {
    int t = blockIdx.x * blockDim.x + threadIdx.x;
    int e = t >> 4, l = t & 15;
    if (e >= Ec) return;
    float4 f = reinterpret_cast<const float4*>(ef)[e * 16 + l];
    float4 w = reinterpret_cast<const float4*>(Fp)[l];
    float s = f.x * w.x + f.y * w.y + f.z * w.z + f.w * w.w;
    s += __shfl_xor(s, 8, 16);
    s += __shfl_xor(s, 4, 16);
    s += __shfl_xor(s, 2, 16);
    s += __shfl_xor(s, 1, 16);
    if (l == 0) ew[e] = s + pb[0];
}

__global__ void k_deg(const int* __restrict__ dst, unsigned* __restrict__ deg) {
    int t = blockIdx.x * blockDim.x + threadIdx.x;
    if (t < 2 * Ec) atomicAdd(&deg[dst[t]], 1u);
}

__global__ void k_dinv(const unsigned* __restrict__ deg, float* __restrict__ dinv) {
    int t = blockIdx.x * blockDim.x + threadIdx.x;
    if (t < Nc) {
        unsigned d = deg[t];
        dinv[t] = d ? rsqrtf((float)d) : 0.f;
    }
}

// --- exclusive prefix sum of deg -> rowptr (3-phase) ---
__global__ void k_scan1(const unsigned* __restrict__ deg, int* __restrict__ rowptr,
                        int* __restrict__ bsums) {
    __shared__ int sh[256];
    int tid = threadIdx.x, bid = blockIdx.x;
    int base = bid * 1024 + tid * 4;
    int v0 = (base + 0 < Nc) ? (int)deg[base + 0] : 0;
    int v1 = (base + 1 < Nc) ? (int)deg[base + 1] : 0;
    int v2 = (base + 2 < Nc) ? (int)deg[base + 2] : 0;
    int v3 = (base + 3 < Nc) ? (int)deg[base + 3] : 0;
    int s = v0 + v1 + v2 + v3;
    sh[tid] = s;
    __syncthreads();
    for (int off = 1; off < 256; off <<= 1) {
        int t = (tid >= off) ? sh[tid - off] : 0;
        __syncthreads();
        sh[tid] += t;
        __syncthreads();
    }
    int excl = sh[tid] - s;
    if (tid == 255) bsums[bid] = sh[255];
    if (base + 0 < Nc) rowptr[base + 0] = excl;
    if (base + 1 < Nc) rowptr[base + 1] = excl + v0;
    if (base + 2 < Nc) rowptr[base + 2] = excl + v0 + v1;
    if (base + 3 < Nc) rowptr[base + 3] = excl + v0 + v1 + v2;
}

__global__ void k_scan2(int* __restrict__ bsums, int nb) {
    __shared__ int sh[256];
    int tid = threadIdx.x;
    int v = (tid < nb) ? bsums[tid] : 0;
    sh[tid] = v;
    __syncthreads();
    for (int off = 1; off < 256; off <<= 1) {
        int t = (tid >= off) ? sh[tid - off] : 0;
        __syncthreads();
        sh[tid] += t;
        __syncthreads();
    }
    if (tid < nb) bsums[tid] = sh[tid] - v;  // exclusive
}

__global__ void k_scan3(int* __restrict__ rowptr, const int* __restrict__ bsums,
                        int* __restrict__ cursor) {
    int i = blockIdx.x * blockDim.x + threadIdx.x;
    if (i < Nc) {
        int r = rowptr[i] + bsums[i >> 10];
        rowptr[i] = r;
        cursor[i] = r;
    }
    if (i == 0) rowptr[Nc] = 2 * Ec;
}

// scatter edges into CSR sorted by dst; coef precomputed
__global__ void k_build(const int* __restrict__ src, const int* __restrict__ dst,
                        const float* __restrict__ ew, const float* __restrict__ dinv,
                        int* __restrict__ cursor, int2* __restrict__ csr) {
    int e = blockIdx.x * blockDim.x + threadIdx.x;
    if (e >= 2 * Ec) return;
    int s = src[e], d = dst[e];
    float c = dinv[s] * dinv[d] * ew[(e >= Ec) ? (e - Ec) : e];
    int pos = atomicAdd(&cursor[d], 1);
    csr[pos] = make_int2(s, __float_as_int(c));
}

__global__ void k_initx(const float* __restrict__ Gu, const float* __restrict__ Gi,
                        float4* __restrict__ x) {
    int t = blockIdx.x * blockDim.x + threadIdx.x;
    if (t >= Nc * 16) return;
    x[t] = (t < Uc * 16) ? reinterpret_cast<const float4*>(Gu)[t]
                         : reinterpret_cast<const float4*>(Gi)[t - Uc * 16];
}

// gather propagation: xn[n] = sum_{e in row n} coef[e] * x[src[e]]
__global__ void k_gprop(const int* __restrict__ rowptr, const int2* __restrict__ csr,
                        const float* __restrict__ x, float* __restrict__ xn) {
    int t = blockIdx.x * blockDim.x + threadIdx.x;
    int n = t >> 4, l = t & 15;
    if (n >= Nc) return;
    int e0 = rowptr[n], e1 = rowptr[n + 1];
    float4 acc = make_float4(0.f, 0.f, 0.f, 0.f);
    for (int e = e0; e < e1; ++e) {
        int2 sc = csr[e];
        float c = __int_as_float(sc.y);
        float4 v = reinterpret_cast<const float4*>(x)[sc.x * 16 + l];
        acc.x += c * v.x;
        acc.y += c * v.y;
        acc.z += c * v.z;
        acc.w += c * v.w;
    }
    reinterpret_cast<float4*>(xn)[n * 16 + l] = acc;
}

__global__ void k_gather(const float* __restrict__ x, const int* __restrict__ users,
                         const int* __restrict__ items, float* __restrict__ accu,
                         float* __restrict__ acci, float alpha, int first) {
    int t = blockIdx.x * blockDim.x + threadIdx.x;
    int r = t >> 4, l = t & 15;
    if (r >= 2 * Bc) return;
    int b, node;
    float* acc;
    if (r < Bc) { b = r; node = users[b]; acc = accu; }
    else        { b = r - Bc; node = Uc + items[b]; acc = acci; }
    float4 v = reinterpret_cast<const float4*>(x)[node * 16 + l];
    float4* ap = reinterpret_cast<float4*>(acc) + b * 16 + l;
    if (first) {
        *ap = make_float4(alpha * v.x, alpha * v.y, alpha * v.z, alpha * v.w);
    } else {
        float4 a = *ap;
        a.x += alpha * v.x; a.y += alpha * v.y; a.z += alpha * v.z; a.w += alpha * v.w;
        *ap = a;
    }
}

__global__ void k_score(const float* __restrict__ accu, const float* __restrict__ acci,
                        float* __restrict__ out) {
    int t = blockIdx.x * blockDim.x + threadIdx.x;
    int b = t >> 4, l = t & 15;
    if (b >= Bc) return;
    float4 a = reinterpret_cast<const float4*>(accu)[b * 16 + l];
    float4 c = reinterpret_cast<const float4*>(acci)[b * 16 + l];
    float s = a.x * c.x + a.y * c.y + a.z * c.z + a.w * c.w;
    s += __shfl_xor(s, 8, 16);
    s += __shfl_xor(s, 4, 16);
    s += __shfl_xor(s, 2, 16);
    s += __shfl_xor(s, 1, 16);
    if (l == 0) out[b] = s;
}

// ---------------- launch ----------------

extern "C" void kernel_launch(void* const* d_in, const int* in_sizes, int n_in,
                              void* d_out, int out_size, void* d_ws, size_t ws_size,
                              hipStream_t stream) {
    const float* Gu = (const float*)d_in[0];
    const float* Gi = (const float*)d_in[1];
    const float* F  = (const float*)d_in[2];
    const float* pw = (const float*)d_in[3];
    const float* pb = (const float*)d_in[4];
    const float* ef = (const float*)d_in[5];
    const int*   ei = (const int*)d_in[6];   // [2, 2E]
    const int* users = (const int*)d_in[7];
    const int* items = (const int*)d_in[8];
    float* out = (float*)d_out;

    float* ws = (float*)d_ws;
    float*    Fp     = ws;                          // 64
    float*    ew     = Fp + 64;                     // E
    float*    dinv   = ew + Ec;                     // N
    unsigned* deg    = (unsigned*)(dinv + Nc);      // N
    int*      rowptr = (int*)(deg + Nc);            // N+16 (padded)
    int*      cursor = rowptr + (Nc + 16);          // N
    int*      bsums  = cursor + Nc;                 // 256
    int2*     csr    = (int2*)(bsums + 256);        // 2E int2
    float*    xa     = (float*)(csr + 2 * Ec);      // N*64
    float*    xb     = xa + (size_t)Nc * 64;        // N*64
    float*    accu   = xb + (size_t)Nc * 64;        // B*64
    float*    acci   = accu + (size_t)Bc * 64;      // B*64

    const int* esrc = ei;
    const int* edst = ei + 2 * Ec;

    hipMemsetAsync(deg, 0, Nc * sizeof(unsigned), stream);
    k_fproj<<<1, 64, 0, stream>>>(F, pw, Fp);
    k_ew<<<(Ec * 16) / 256, 256, 0, stream>>>(ef, Fp, pb, ew);
    k_deg<<<(2 * Ec + 255) / 256, 256, 0, stream>>>(edst, deg);
    k_dinv<<<(Nc + 255) / 256, 256, 0, stream>>>(deg, dinv);
    k_scan1<<<NBS, 256, 0, stream>>>(deg, rowptr, bsums);
    k_scan2<<<1, 256, 0, stream>>>(bsums, NBS);
    k_scan3<<<(Nc + 255) / 256, 256, 0, stream>>>(rowptr, bsums, cursor);
    k_build<<<(2 * Ec + 255) / 256, 256, 0, stream>>>(esrc, edst, ew, dinv, cursor, csr);
    k_initx<<<(Nc * 16 + 255) / 256, 256, 0, stream>>>(Gu, Gi, (float4*)xa);
    k_gather<<<(2 * Bc * 16) / 256, 256, 0, stream>>>(xa, users, items, accu, acci, 1.0f, 1);

    const float alphas[3] = {0.5f, 1.f / 3.f, 0.25f};
    float* xc = xa;
    float* xn = xb;
    for (int k = 0; k < 3; ++k) {
        k_gprop<<<(Nc * 16 + 255) / 256, 256, 0, stream>>>(rowptr, csr, xc, xn);
        k_gather<<<(2 * Bc * 16) / 256, 256, 0, stream>>>(xn, users, items, accu, acci, alphas[k], 0);
        float* tmp = xc; xc = xn; xn = tmp;
    }
    k_score<<<(Bc * 16) / 256, 256, 0, stream>>>(accu, acci, out);
}

// Round 3
// 483.271 us; speedup vs baseline: 10.3720x; 1.2093x over previous
//
#include <hip/hip_runtime.h>

constexpr int Uc = 100000;
constexpr int Ic = 50000;
constexpr int Nc = 150000;   // U + I
constexpr int Ec = 1000000;
constexpr int Bc = 16384;
constexpr int NBS = (Nc + 1023) / 1024;  // scan blocks = 147

// ---------------- kernels ----------------

// Fp[d] = sum_j F[d][j] * proj_w[j]
__global__ void k_fproj(const float* __restrict__ F, const float* __restrict__ pw,
                        float* __restrict__ Fp) {
    int d = threadIdx.x;
    if (d < 64) {
        float s = 0.f;
#pragma unroll
        for (int j = 0; j < 64; ++j) s += F[d * 64 + j] * pw[j];
        Fp[d] = s;
    }
}

// ew[e] = dot(edge_features[e,:], Fp) + proj_b ; 16 lanes per edge
__global__ void k_ew(const float* __restrict__ ef, const float* __restrict__ Fp,
                     const float* __restrict__ pb, float* __restrict__ ew) {
    int t = blockIdx.x * blockDim.x + threadIdx.x;
    int e = t >> 4, l = t & 15;
    if (e >= Ec) return;
    float4 f = reinterpret_cast<const float4*>(ef)[e * 16 + l];
    float4 w = reinterpret_cast<const float4*>(Fp)[l];
    float s = f.x * w.x + f.y * w.y + f.z * w.z + f.w * w.w;
    s += __shfl_xor(s, 8, 16);
    s += __shfl_xor(s, 4, 16);
    s += __shfl_xor(s, 2, 16);
    s += __shfl_xor(s, 1, 16);
    if (l == 0) ew[e] = s + pb[0];
}

__global__ void k_deg(const int* __restrict__ dst, unsigned* __restrict__ deg) {
    int t = blockIdx.x * blockDim.x + threadIdx.x;
    if (t < 2 * Ec) atomicAdd(&deg[dst[t]], 1u);
}

// --- scan phase 1: per-1024-chunk exclusive scan of deg; also writes dinv ---
__global__ void k_scan1(const unsigned* __restrict__ deg, int* __restrict__ rowptr,
                        int* __restrict__ bsums, float* __restrict__ dinv) {
    __shared__ int sh[256];
    int tid = threadIdx.x, bid = blockIdx.x;
    int base = bid * 1024 + tid * 4;
    int v0 = (base + 0 < Nc) ? (int)deg[base + 0] : 0;
    int v1 = (base + 1 < Nc) ? (int)deg[base + 1] : 0;
    int v2 = (base + 2 < Nc) ? (int)deg[base + 2] : 0;
    int v3 = (base + 3 < Nc) ? (int)deg[base + 3] : 0;
    if (base + 0 < Nc) dinv[base + 0] = v0 ? rsqrtf((float)v0) : 0.f;
    if (base + 1 < Nc) dinv[base + 1] = v1 ? rsqrtf((float)v1) : 0.f;
    if (base + 2 < Nc) dinv[base + 2] = v2 ? rsqrtf((float)v2) : 0.f;
    if (base + 3 < Nc) dinv[base + 3] = v3 ? rsqrtf((float)v3) : 0.f;
    int s = v0 + v1 + v2 + v3;
    sh[tid] = s;
    __syncthreads();
    for (int off = 1; off < 256; off <<= 1) {
        int t = (tid >= off) ? sh[tid - off] : 0;
        __syncthreads();
        sh[tid] += t;
        __syncthreads();
    }
    int excl = sh[tid] - s;
    if (tid == 255) bsums[bid] = sh[255];
    if (base + 0 < Nc) rowptr[base + 0] = excl;
    if (base + 1 < Nc) rowptr[base + 1] = excl + v0;
    if (base + 2 < Nc) rowptr[base + 2] = excl + v0 + v1;
    if (base + 3 < Nc) rowptr[base + 3] = excl + v0 + v1 + v2;
}

__global__ void k_scan2(int* __restrict__ bsums, int nb) {
    __shared__ int sh[256];
    int tid = threadIdx.x;
    int v = (tid < nb) ? bsums[tid] : 0;
    sh[tid] = v;
    __syncthreads();
    for (int off = 1; off < 256; off <<= 1) {
        int t = (tid >= off) ? sh[tid - off] : 0;
        __syncthreads();
        sh[tid] += t;
        __syncthreads();
    }
    if (tid < nb) bsums[tid] = sh[tid] - v;  // exclusive
}

__global__ void k_scan3(int* __restrict__ rowptr, const int* __restrict__ bsums,
                        int* __restrict__ cursor) {
    int i = blockIdx.x * blockDim.x + threadIdx.x;
    if (i < Nc) {
        int r = rowptr[i] + bsums[i >> 10];
        rowptr[i] = r;
        cursor[i] = r;
    }
    if (i == 0) rowptr[Nc] = 2 * Ec;
}

// scatter edges into CSR sorted by dst; coef precomputed
__global__ void k_build(const int* __restrict__ src, const int* __restrict__ dst,
                        const float* __restrict__ ew, const float* __restrict__ dinv,
                        int* __restrict__ cursor, int2* __restrict__ csr) {
    int e = blockIdx.x * blockDim.x + threadIdx.x;
    if (e >= 2 * Ec) return;
    int s = src[e], d = dst[e];
    float c = dinv[s] * dinv[d] * ew[(e >= Ec) ? (e - Ec) : e];
    int pos = atomicAdd(&cursor[d], 1);
    csr[pos] = make_int2(s, __float_as_int(c));
}

// gather propagation, full graph. SPLIT=1: layer-1, sources from Gu/Gi
// (bipartite: dst<U reads only item rows; dst>=U reads only user rows).
template <int SPLIT>
__global__ void k_gprop(const int* __restrict__ rowptr, const int2* __restrict__ csr,
                        const float* __restrict__ xGu, const float* __restrict__ xGi,
                        float* __restrict__ xn) {
    int t = blockIdx.x * blockDim.x + threadIdx.x;
    int n = t >> 4, l = t & 15;
    if (n >= Nc) return;
    int e0 = rowptr[n], e1 = rowptr[n + 1];
    const float4* xs;
    int off;
    if (SPLIT) {  // uniform per node-group
        if (n < Uc) { xs = reinterpret_cast<const float4*>(xGi); off = Uc * 16; }
        else        { xs = reinterpret_cast<const float4*>(xGu); off = 0; }
    } else {
        xs = reinterpret_cast<const float4*>(xGu); off = 0;
    }
    float4 acc = make_float4(0.f, 0.f, 0.f, 0.f);
    for (int e = e0; e < e1; ++e) {
        int2 sc = csr[e];
        float c = __int_as_float(sc.y);
        float4 v = xs[sc.x * 16 - off + l];
        acc.x += c * v.x;
        acc.y += c * v.y;
        acc.z += c * v.z;
        acc.w += c * v.w;
    }
    reinterpret_cast<float4*>(xn)[n * 16 + l] = acc;
}

// batch-restricted layer-3 gprop: acc[b] += alpha * sum_e coef * x[src]
__global__ void k_gprop_batch(const int* __restrict__ rowptr, const int2* __restrict__ csr,
                              const float* __restrict__ x, const int* __restrict__ users,
                              const int* __restrict__ items, float* __restrict__ accu,
                              float* __restrict__ acci, float alpha) {
    int t = blockIdx.x * blockDim.x + threadIdx.x;
    int r = t >> 4, l = t & 15;
    if (r >= 2 * Bc) return;
    int b, n;
    float* acc;
    if (r < Bc) { b = r; n = users[b]; acc = accu; }
    else        { b = r - Bc; n = Uc + items[b]; acc = acci; }
    int e0 = rowptr[n], e1 = rowptr[n + 1];
    float4 s = make_float4(0.f, 0.f, 0.f, 0.f);
    const float4* xs = reinterpret_cast<const float4*>(x);
    for (int e = e0; e < e1; ++e) {
        int2 sc = csr[e];
        float c = __int_as_float(sc.y);
        float4 v = xs[sc.x * 16 + l];
        s.x += c * v.x;
        s.y += c * v.y;
        s.z += c * v.z;
        s.w += c * v.w;
    }
    float4* ap = reinterpret_cast<float4*>(acc) + b * 16 + l;
    float4 a = *ap;
    a.x += alpha * s.x; a.y += alpha * s.y; a.z += alpha * s.z; a.w += alpha * s.w;
    *ap = a;
}

// acc accumulate from a full x (or split Gu/Gi for layer 0)
template <int SPLIT>
__global__ void k_gather(const float* __restrict__ xGu, const float* __restrict__ xGi,
                         const int* __restrict__ users, const int* __restrict__ items,
                         float* __restrict__ accu, float* __restrict__ acci,
                         float alpha, int first) {
    int t = blockIdx.x * blockDim.x + threadIdx.x;
    int r = t >> 4, l = t & 15;
    if (r >= 2 * Bc) return;
    int b;
    const float4* xs;
    int node;
    float* acc;
    if (r < Bc) {
        b = r; acc = accu;
        if (SPLIT) { xs = reinterpret_cast<const float4*>(xGu); node = users[b]; }
        else       { xs = reinterpret_cast<const float4*>(xGu); node = users[b]; }
    } else {
        b = r - Bc; acc = acci;
        if (SPLIT) { xs = reinterpret_cast<const float4*>(xGi); node = items[b]; }
        else       { xs = reinterpret_cast<const float4*>(xGu); node = Uc + items[b]; }
    }
    float4 v = xs[node * 16 + l];
    float4* ap = reinterpret_cast<float4*>(acc) + b * 16 + l;
    if (first) {
        *ap = make_float4(alpha * v.x, alpha * v.y, alpha * v.z, alpha * v.w);
    } else {
        float4 a = *ap;
        a.x += alpha * v.x; a.y += alpha * v.y; a.z += alpha * v.z; a.w += alpha * v.w;
        *ap = a;
    }
}

__global__ void k_score(const float* __restrict__ accu, const float* __restrict__ acci,
                        float* __restrict__ out) {
    int t = blockIdx.x * blockDim.x + threadIdx.x;
    int b = t >> 4, l = t & 15;
    if (b >= Bc) return;
    float4 a = reinterpret_cast<const float4*>(accu)[b * 16 + l];
    float4 c = reinterpret_cast<const float4*>(acci)[b * 16 + l];
    float s = a.x * c.x + a.y * c.y + a.z * c.z + a.w * c.w;
    s += __shfl_xor(s, 8, 16);
    s += __shfl_xor(s, 4, 16);
    s += __shfl_xor(s, 2, 16);
    s += __shfl_xor(s, 1, 16);
    if (l == 0) out[b] = s;
}

// ---------------- launch ----------------

extern "C" void kernel_launch(void* const* d_in, const int* in_sizes, int n_in,
                              void* d_out, int out_size, void* d_ws, size_t ws_size,
                              hipStream_t stream) {
    const float* Gu = (const float*)d_in[0];
    const float* Gi = (const float*)d_in[1];
    const float* F  = (const float*)d_in[2];
    const float* pw = (const float*)d_in[3];
    const float* pb = (const float*)d_in[4];
    const float* ef = (const float*)d_in[5];
    const int*   ei = (const int*)d_in[6];   // [2, 2E]
    const int* users = (const int*)d_in[7];
    const int* items = (const int*)d_in[8];
    float* out = (float*)d_out;

    float* ws = (float*)d_ws;
    float*    Fp     = ws;                          // 64
    float*    ew     = Fp + 64;                     // E
    float*    dinv   = ew + Ec;                     // N
    unsigned* deg    = (unsigned*)(dinv + Nc);      // N
    int*      rowptr = (int*)(deg + Nc);            // N+16 (padded)
    int*      cursor = rowptr + (Nc + 16);          // N
    int*      bsums  = cursor + Nc;                 // 256
    int2*     csr    = (int2*)(bsums + 256);        // 2E int2
    float*    xa     = (float*)(csr + 2 * Ec);      // N*64
    float*    xb     = xa + (size_t)Nc * 64;        // N*64
    float*    accu   = xb + (size_t)Nc * 64;        // B*64
    float*    acci   = accu + (size_t)Bc * 64;      // B*64

    const int* esrc = ei;
    const int* edst = ei + 2 * Ec;

    hipMemsetAsync(deg, 0, Nc * sizeof(unsigned), stream);
    k_fproj<<<1, 64, 0, stream>>>(F, pw, Fp);
    k_ew<<<(Ec * 16) / 256, 256, 0, stream>>>(ef, Fp, pb, ew);
    k_deg<<<(2 * Ec + 255) / 256, 256, 0, stream>>>(edst, deg);
    k_scan1<<<NBS, 256, 0, stream>>>(deg, rowptr, bsums, dinv);
    k_scan2<<<1, 256, 0, stream>>>(bsums, NBS);
    k_scan3<<<(Nc + 255) / 256, 256, 0, stream>>>(rowptr, bsums, cursor);
    k_build<<<(2 * Ec + 255) / 256, 256, 0, stream>>>(esrc, edst, ew, dinv, cursor, csr);

    // alpha_0 gather straight from inputs (no initx)
    k_gather<1><<<(2 * Bc * 16) / 256, 256, 0, stream>>>(Gu, Gi, users, items, accu, acci, 1.0f, 1);

    // layer 1: sources are the inputs (bipartite split), write xa
    k_gprop<1><<<(Nc * 16 + 255) / 256, 256, 0, stream>>>(rowptr, csr, Gu, Gi, xa);
    k_gather<0><<<(2 * Bc * 16) / 256, 256, 0, stream>>>(xa, nullptr, users, items, accu, acci, 0.5f, 0);

    // layer 2: xa -> xb
    k_gprop<0><<<(Nc * 16 + 255) / 256, 256, 0, stream>>>(rowptr, csr, xa, nullptr, xb);
    k_gather<0><<<(2 * Bc * 16) / 256, 256, 0, stream>>>(xb, nullptr, users, items, accu, acci, 1.f / 3.f, 0);

    // layer 3: batch-restricted, accumulate alpha_3 directly
    k_gprop_batch<<<(2 * Bc * 16) / 256, 256, 0, stream>>>(rowptr, csr, xb, users, items, accu, acci, 0.25f);

    k_score<<<(Bc * 16) / 256, 256, 0, stream>>>(accu, acci, out);
}

// Round 4
// 403.113 us; speedup vs baseline: 12.4344x; 1.1988x over previous
//
#include <hip/hip_runtime.h>

constexpr int Uc = 100000;
constexpr int Ic = 50000;
constexpr int Nc = 150000;   // U + I
constexpr int Ec = 1000000;
constexpr int Bc = 16384;
constexpr int NBS = (Nc + 1023) / 1024;  // scan blocks = 147

// ---------------- kernels ----------------

// Fp[d] = sum_j F[d][j] * proj_w[j]
__global__ void k_fproj(const float* __restrict__ F, const float* __restrict__ pw,
                        float* __restrict__ Fp) {
    int d = threadIdx.x;
    if (d < 64) {
        float s = 0.f;
#pragma unroll
        for (int j = 0; j < 64; ++j) s += F[d * 64 + j] * pw[j];
        Fp[d] = s;
    }
}

// degree over undirected edges: deg[u]++, deg[it]++  (dst multiset == src multiset)
__global__ void k_deg2(const int* __restrict__ un, const int* __restrict__ in_,
                       unsigned* __restrict__ deg) {
    int e = blockIdx.x * blockDim.x + threadIdx.x;
    if (e < Ec) {
        atomicAdd(&deg[un[e]], 1u);
        atomicAdd(&deg[in_[e]], 1u);
    }
}

// --- scan phase 1: per-1024-chunk exclusive scan of deg; also writes dinv ---
__global__ void k_scan1(const unsigned* __restrict__ deg, int* __restrict__ rowptr,
                        int* __restrict__ bsums, float* __restrict__ dinv) {
    __shared__ int sh[256];
    int tid = threadIdx.x, bid = blockIdx.x;
    int base = bid * 1024 + tid * 4;
    int v0 = (base + 0 < Nc) ? (int)deg[base + 0] : 0;
    int v1 = (base + 1 < Nc) ? (int)deg[base + 1] : 0;
    int v2 = (base + 2 < Nc) ? (int)deg[base + 2] : 0;
    int v3 = (base + 3 < Nc) ? (int)deg[base + 3] : 0;
    if (base + 0 < Nc) dinv[base + 0] = v0 ? rsqrtf((float)v0) : 0.f;
    if (base + 1 < Nc) dinv[base + 1] = v1 ? rsqrtf((float)v1) : 0.f;
    if (base + 2 < Nc) dinv[base + 2] = v2 ? rsqrtf((float)v2) : 0.f;
    if (base + 3 < Nc) dinv[base + 3] = v3 ? rsqrtf((float)v3) : 0.f;
    int s = v0 + v1 + v2 + v3;
    sh[tid] = s;
    __syncthreads();
    for (int off = 1; off < 256; off <<= 1) {
        int t = (tid >= off) ? sh[tid - off] : 0;
        __syncthreads();
        sh[tid] += t;
        __syncthreads();
    }
    int excl = sh[tid] - s;
    if (tid == 255) bsums[bid] = sh[255];
    if (base + 0 < Nc) rowptr[base + 0] = excl;
    if (base + 1 < Nc) rowptr[base + 1] = excl + v0;
    if (base + 2 < Nc) rowptr[base + 2] = excl + v0 + v1;
    if (base + 3 < Nc) rowptr[base + 3] = excl + v0 + v1 + v2;
}

__global__ void k_scan2(int* __restrict__ bsums, int nb) {
    __shared__ int sh[256];
    int tid = threadIdx.x;
    int v = (tid < nb) ? bsums[tid] : 0;
    sh[tid] = v;
    __syncthreads();
    for (int off = 1; off < 256; off <<= 1) {
        int t = (tid >= off) ? sh[tid - off] : 0;
        __syncthreads();
        sh[tid] += t;
        __syncthreads();
    }
    if (tid < nb) bsums[tid] = sh[tid] - v;  // exclusive
}

__global__ void k_scan3(int* __restrict__ rowptr, const int* __restrict__ bsums,
                        int* __restrict__ cursor) {
    int i = blockIdx.x * blockDim.x + threadIdx.x;
    if (i < Nc) {
        int r = rowptr[i] + bsums[i >> 10];
        rowptr[i] = r;
        cursor[i] = r;
    }
    if (i == 0) rowptr[Nc] = 2 * Ec;
}

// fused: edge-weight projection + CSR scatter (both directions, same coef)
// 16 lanes per undirected edge
__global__ void k_build(const int* __restrict__ un, const int* __restrict__ in_,
                        const float* __restrict__ ef, const float* __restrict__ Fp,
                        const float* __restrict__ pb, const float* __restrict__ dinv,
                        int* __restrict__ cursor, int2* __restrict__ csr) {
    int t = blockIdx.x * blockDim.x + threadIdx.x;
    int e = t >> 4, l = t & 15;
    if (e >= Ec) return;
    float4 f = reinterpret_cast<const float4*>(ef)[(size_t)e * 16 + l];
    float4 w = reinterpret_cast<const float4*>(Fp)[l];
    float s = f.x * w.x + f.y * w.y + f.z * w.z + f.w * w.w;
    s += __shfl_xor(s, 8, 16);
    s += __shfl_xor(s, 4, 16);
    s += __shfl_xor(s, 2, 16);
    s += __shfl_xor(s, 1, 16);
    if (l == 0 || l == 8) {
        int uu = un[e], ii = in_[e];
        float c = dinv[uu] * dinv[ii] * (s + pb[0]);
        if (l == 0) {
            int pos = atomicAdd(&cursor[ii], 1);
            csr[pos] = make_int2(uu, __float_as_int(c));
        } else {
            int pos = atomicAdd(&cursor[uu], 1);
            csr[pos] = make_int2(ii, __float_as_int(c));
        }
    }
}

// gather propagation, full graph, 4x ILP-unrolled edge loop.
// SPLIT=1: layer-1, sources come straight from Gu/Gi (bipartite).
template <int SPLIT>
__global__ void k_gprop(const int* __restrict__ rowptr, const int2* __restrict__ csr,
                        const float* __restrict__ xGu, const float* __restrict__ xGi,
                        float* __restrict__ xn) {
    int t = blockIdx.x * blockDim.x + threadIdx.x;
    int n = t >> 4, l = t & 15;
    if (n >= Nc) return;
    int e0 = rowptr[n], e1 = rowptr[n + 1];
    const float4* xs;
    int off = 0;
    if (SPLIT) {
        if (n < Uc) { xs = reinterpret_cast<const float4*>(xGi); off = Uc * 16; }
        else        { xs = reinterpret_cast<const float4*>(xGu); }
    } else {
        xs = reinterpret_cast<const float4*>(xGu);
    }
    float4 acc = make_float4(0.f, 0.f, 0.f, 0.f);
    int e = e0;
    for (; e + 4 <= e1; e += 4) {
        int2 s0 = csr[e], s1 = csr[e + 1], s2 = csr[e + 2], s3 = csr[e + 3];
        float4 v0 = xs[s0.x * 16 - off + l];
        float4 v1 = xs[s1.x * 16 - off + l];
        float4 v2 = xs[s2.x * 16 - off + l];
        float4 v3 = xs[s3.x * 16 - off + l];
        float c0 = __int_as_float(s0.y), c1 = __int_as_float(s1.y);
        float c2 = __int_as_float(s2.y), c3 = __int_as_float(s3.y);
        acc.x += c0 * v0.x + c1 * v1.x + c2 * v2.x + c3 * v3.x;
        acc.y += c0 * v0.y + c1 * v1.y + c2 * v2.y + c3 * v3.y;
        acc.z += c0 * v0.z + c1 * v1.z + c2 * v2.z + c3 * v3.z;
        acc.w += c0 * v0.w + c1 * v1.w + c2 * v2.w + c3 * v3.w;
    }
    for (; e < e1; ++e) {
        int2 sc = csr[e];
        float c = __int_as_float(sc.y);
        float4 v = xs[sc.x * 16 - off + l];
        acc.x += c * v.x; acc.y += c * v.y; acc.z += c * v.z; acc.w += c * v.w;
    }
    reinterpret_cast<float4*>(xn)[n * 16 + l] = acc;
}

// fused batch-side: acc_u/acc_i = sum_k alpha_k x_k[node] (+ layer-3 on the fly),
// then dot. One 64-lane wave per (user,item) pair; lane = feature dim.
__global__ void k_final(const float* __restrict__ Gu, const float* __restrict__ Gi,
                        const float* __restrict__ x1, const float* __restrict__ x2,
                        const int* __restrict__ rowptr, const int2* __restrict__ csr,
                        const int* __restrict__ users, const int* __restrict__ items,
                        float* __restrict__ out) {
    int wid = (blockIdx.x * blockDim.x + threadIdx.x) >> 6;
    int d = threadIdx.x & 63;
    if (wid >= Bc) return;
    int un = users[wid];
    int in_ = Uc + items[wid];

    float acc2[2];
#pragma unroll
    for (int side = 0; side < 2; ++side) {
        int n = side ? in_ : un;
        float base = side ? Gi[(size_t)(n - Uc) * 64 + d] : Gu[(size_t)n * 64 + d];
        float a = base + 0.5f * x1[(size_t)n * 64 + d] + (1.f / 3.f) * x2[(size_t)n * 64 + d];
        float su = 0.f;
        int e0 = rowptr[n], e1 = rowptr[n + 1];
        int e = e0;
        for (; e + 4 <= e1; e += 4) {
            int2 s0 = csr[e], s1 = csr[e + 1], s2 = csr[e + 2], s3 = csr[e + 3];
            float v0 = x2[(size_t)s0.x * 64 + d];
            float v1 = x2[(size_t)s1.x * 64 + d];
            float v2 = x2[(size_t)s2.x * 64 + d];
            float v3 = x2[(size_t)s3.x * 64 + d];
            su += __int_as_float(s0.y) * v0 + __int_as_float(s1.y) * v1 +
                  __int_as_float(s2.y) * v2 + __int_as_float(s3.y) * v3;
        }
        for (; e < e1; ++e) {
            int2 sc = csr[e];
            su += __int_as_float(sc.y) * x2[(size_t)sc.x * 64 + d];
        }
        acc2[side] = a + 0.25f * su;
    }

    float p = acc2[0] * acc2[1];
#pragma unroll
    for (int o = 32; o > 0; o >>= 1) p += __shfl_xor(p, o, 64);
    if (d == 0) out[wid] = p;
}

// ---------------- launch ----------------

extern "C" void kernel_launch(void* const* d_in, const int* in_sizes, int n_in,
                              void* d_out, int out_size, void* d_ws, size_t ws_size,
                              hipStream_t stream) {
    const float* Gu = (const float*)d_in[0];
    const float* Gi = (const float*)d_in[1];
    const float* F  = (const float*)d_in[2];
    const float* pw = (const float*)d_in[3];
    const float* pb = (const float*)d_in[4];
    const float* ef = (const float*)d_in[5];
    const int*   ei = (const int*)d_in[6];   // [2, 2E]
    const int* users = (const int*)d_in[7];
    const int* items = (const int*)d_in[8];
    float* out = (float*)d_out;

    float* ws = (float*)d_ws;
    float*    Fp     = ws;                          // 64
    float*    dinv   = Fp + 64;                     // N
    unsigned* deg    = (unsigned*)(dinv + Nc);      // N
    int*      rowptr = (int*)(deg + Nc);            // N+16
    int*      cursor = rowptr + (Nc + 16);          // N
    int*      bsums  = cursor + Nc;                 // 256
    int2*     csr    = (int2*)(bsums + 256);        // 2E int2
    float*    xa     = (float*)(csr + 2 * Ec);      // N*64
    float*    xb     = xa + (size_t)Nc * 64;        // N*64

    const int* un  = ei;            // first row, first half  = user ids
    const int* in_ = ei + 2 * Ec;   // second row, first half = item node ids (>=U)

    hipMemsetAsync(deg, 0, Nc * sizeof(unsigned), stream);
    k_fproj<<<1, 64, 0, stream>>>(F, pw, Fp);
    k_deg2<<<(Ec + 255) / 256, 256, 0, stream>>>(un, in_, deg);
    k_scan1<<<NBS, 256, 0, stream>>>(deg, rowptr, bsums, dinv);
    k_scan2<<<1, 256, 0, stream>>>(bsums, NBS);
    k_scan3<<<(Nc + 255) / 256, 256, 0, stream>>>(rowptr, bsums, cursor);
    k_build<<<(Ec * 16) / 256, 256, 0, stream>>>(un, in_, ef, Fp, pb, dinv, cursor, csr);

    // layer 1: inputs -> xa ; layer 2: xa -> xb
    k_gprop<1><<<(Nc * 16 + 255) / 256, 256, 0, stream>>>(rowptr, csr, Gu, Gi, xa);
    k_gprop<0><<<(Nc * 16 + 255) / 256, 256, 0, stream>>>(rowptr, csr, xa, nullptr, xb);

    // fused: alpha-weighted batch accumulation + layer-3 on the fly + dot
    k_final<<<(Bc * 64) / 256, 256, 0, stream>>>(Gu, Gi, xa, xb, rowptr, csr, users, items, out);
}